// Round 4
// baseline (433.731 us; speedup 1.0000x reference)
//
#include <hip/hip_runtime.h>

// ---------------- constants for this problem ----------------
// N_NODES=100000, N_EDGES=1600000, IN_FEATS=128, H=4, D=32, HD=128, NUM_ETYPES=8, DROP_BLOCKS=4
// Bucket = 64 consecutive dst nodes. Packed bucket entry: src[0:17) | etype[17:20) | (dst&63)[20:26)

typedef short short8 __attribute__((ext_vector_type(8)));
typedef float f32x4 __attribute__((ext_vector_type(4)));

__device__ inline unsigned short f2bf(float x) {
    unsigned u = __builtin_bit_cast(unsigned, x);
    u += 0x7FFFu + ((u >> 16) & 1u);   // RNE
    return (unsigned short)(u >> 16);
}

// K1: per-node etype histogram
__global__ void k_hist(const int* __restrict__ e_feat, const int* __restrict__ dst,
                       unsigned* __restrict__ cnt, int E) {
    int i = blockIdx.x * 256 + threadIdx.x;
    if (i < E) atomicAdd(&cnt[(unsigned)dst[i] * 8u + (unsigned)e_feat[i]], 1u);
}

// K2: per-node softmax stats: m[h], 1/s[h], deg
__global__ void k_stats(const unsigned* __restrict__ cnt, const float* __restrict__ emb,
                        float* __restrict__ stats, unsigned* __restrict__ deg, int N) {
    __shared__ float se[32];
    int t = threadIdx.x;
    if (t < 32) se[t] = emb[t];
    __syncthreads();
    int n = blockIdx.x * 256 + t;
    if (n >= N) return;
    uint4 a = *(const uint4*)(cnt + (size_t)n * 8);
    uint4 b = *(const uint4*)(cnt + (size_t)n * 8 + 4);
    unsigned c[8] = {a.x, a.y, a.z, a.w, b.x, b.y, b.z, b.w};
    unsigned dg = 0;
#pragma unroll
    for (int j = 0; j < 8; ++j) dg += c[j];
    deg[n] = dg;
#pragma unroll
    for (int h = 0; h < 4; ++h) {
        float m = -3.4e38f;
#pragma unroll
        for (int tt = 0; tt < 8; ++tt)
            if (c[tt]) m = fmaxf(m, se[tt * 4 + h]);
        float s = 0.f;
#pragma unroll
        for (int tt = 0; tt < 8; ++tt)
            if (c[tt]) s += (float)c[tt] * expf(se[tt * 4 + h] - m);
        stats[(size_t)n * 8 + h] = m;
        stats[(size_t)n * 8 + 4 + h] = dg ? (1.0f / s) : 0.0f;
    }
}

// K3a: per-block partial sums of deg
__global__ void k_scan_part(const unsigned* __restrict__ deg, unsigned* __restrict__ part, int N) {
    __shared__ unsigned s[256];
    int t = threadIdx.x;
    int n = blockIdx.x * 256 + t;
    s[t] = (n < N) ? deg[n] : 0u;
    __syncthreads();
    for (int of = 128; of > 0; of >>= 1) {
        if (t < of) s[t] += s[t + of];
        __syncthreads();
    }
    if (t == 0) part[blockIdx.x] = s[0];
}

// K3b: single-block exclusive scan of partials (NB <= 512)
__global__ void k_scan_block(const unsigned* __restrict__ part, unsigned* __restrict__ base, int NB) {
    __shared__ unsigned s[512];
    int t = threadIdx.x;
    s[t] = (t < NB) ? part[t] : 0u;
    __syncthreads();
    for (int of = 1; of < 512; of <<= 1) {
        unsigned v = (t >= of) ? s[t - of] : 0u;
        __syncthreads();
        s[t] += v;
        __syncthreads();
    }
    if (t < NB) base[t] = t ? s[t - 1] : 0u;
}

// K3c: per-node exclusive offsets
__global__ void k_scan_offs(const unsigned* __restrict__ deg, const unsigned* __restrict__ base,
                            unsigned* __restrict__ offs, int N) {
    __shared__ unsigned s[256];
    int t = threadIdx.x;
    int n = blockIdx.x * 256 + t;
    unsigned d = (n < N) ? deg[n] : 0u;
    s[t] = d;
    __syncthreads();
    for (int of = 1; of < 256; of <<= 1) {
        unsigned v = (t >= of) ? s[t - of] : 0u;
        __syncthreads();
        s[t] += v;
        __syncthreads();
    }
    if (n < N) offs[n] = base[blockIdx.x] + s[t] - d;
}

// K4: bucket-partition edges (64 nodes/bucket) + fused attn_out write.
// Bucket region in csr2 = [offs[b*64], offs[(b+1)*64)) — append via bcur[b].
__global__ void k_bucket(const int* __restrict__ src, const int* __restrict__ dst,
                         const int* __restrict__ e_feat, const unsigned* __restrict__ offs,
                         unsigned* __restrict__ bcur, unsigned* __restrict__ csr2,
                         const float* __restrict__ emb, const float* __restrict__ stats,
                         float4* __restrict__ ao, int E) {
    int e = blockIdx.x * 256 + threadIdx.x;
    if (e >= E) return;
    int d = dst[e];
    int tt = e_feat[e];
    int s = src[e];
    unsigned b = (unsigned)d >> 6;
    unsigned pos = offs[b << 6] + atomicAdd(&bcur[b], 1u);
    csr2[pos] = (unsigned)s | ((unsigned)tt << 17) | ((unsigned)(d & 63) << 20);
    // fused attn_out
    const float4* st4 = (const float4*)(stats + (size_t)d * 8);
    float4 m4 = st4[0], i4 = st4[1];
    const float4* em4 = (const float4*)(emb + tt * 4);
    float4 ee = *em4;
    float a0 = expf(ee.x - m4.x) * i4.x;
    float a1 = expf(ee.y - m4.y) * i4.y;
    float a2 = expf(ee.z - m4.z) * i4.z;
    float a3 = expf(ee.w - m4.w) * i4.w;
    float4* aop = ao + (size_t)e * 4;
    aop[0] = make_float4(a0, a0, a0, a0);
    aop[1] = make_float4(a1, a1, a1, a1);
    aop[2] = make_float4(a2, a2, a2, a2);
    aop[3] = make_float4(a3, a3, a3, a3);
}

// K5: within-bucket counting sort -> final CSR (grouped by node).
// One block per bucket; writes confined to the bucket's contiguous region.
__global__ __launch_bounds__(256) void k_bsort(const unsigned* __restrict__ csr2,
                                               const unsigned* __restrict__ offs,
                                               unsigned* __restrict__ csr, int N, int E) {
    __shared__ unsigned cnt[64];
    __shared__ unsigned basev[64];
    int b = blockIdx.x;
    int tid = threadIdx.x;
    int n0 = b << 6;
    int n1 = n0 + 64; if (n1 > N) n1 = N;
    unsigned r0 = offs[n0];
    unsigned r1 = (n1 == N) ? (unsigned)E : offs[n1];
    if (tid < 64) cnt[tid] = 0u;
    __syncthreads();
    for (unsigned i = r0 + tid; i < r1; i += 256)
        atomicAdd(&cnt[(csr2[i] >> 20) & 63u], 1u);
    __syncthreads();
    if (tid < 64) {
        unsigned orig = cnt[tid];
        unsigned v = orig;
#pragma unroll
        for (int of = 1; of < 64; of <<= 1) {
            unsigned u = __shfl_up(v, of, 64);
            if (tid >= of) v += u;
        }
        basev[tid] = v - orig;
        cnt[tid] = 0u;   // reuse as cursor (same wave, safe)
    }
    __syncthreads();
    for (unsigned i = r0 + tid; i < r1; i += 256) {
        unsigned en = csr2[i];
        unsigned nlo = (en >> 20) & 63u;
        unsigned pos = r0 + basev[nlo] + atomicAdd(&cnt[nlo], 1u);
        csr[pos] = (en & 0x1FFFFu) | (((en >> 17) & 7u) << 20);
    }
}

// K6: ft = feat @ W^T via bf16 MFMA; output stored as bf16 for the gather.
__global__ __launch_bounds__(256) void k_gemm_mfma(const float* __restrict__ feat,
                                                   const float* __restrict__ W,
                                                   unsigned short* __restrict__ ftb, int N) {
    __shared__ unsigned short As[128 * 128];  // 32 KB
    __shared__ unsigned short Bs[128 * 128];  // 32 KB
    int tid = threadIdx.x;
    int row0 = blockIdx.x * 128;

#pragma unroll
    for (int it = 0; it < 16; ++it) {
        int i = it * 1024 + tid * 4;
        int r = i >> 7, c = i & 127;
        unsigned swz = (unsigned)((r & 7) << 4);
        float4 w4 = *(const float4*)(W + i);
        ushort4 wb;
        wb.x = f2bf(w4.x); wb.y = f2bf(w4.y); wb.z = f2bf(w4.z); wb.w = f2bf(w4.w);
        *(ushort4*)((char*)Bs + (((unsigned)(r * 256 + c * 2)) ^ swz)) = wb;
        int gr = row0 + r;
        float4 a4 = make_float4(0.f, 0.f, 0.f, 0.f);
        if (gr < N) a4 = *(const float4*)(feat + (size_t)gr * 128 + c);
        ushort4 ab;
        ab.x = f2bf(a4.x); ab.y = f2bf(a4.y); ab.z = f2bf(a4.z); ab.w = f2bf(a4.w);
        *(ushort4*)((char*)As + (((unsigned)(r * 256 + c * 2)) ^ swz)) = ab;
    }
    __syncthreads();

    int wv = tid >> 6, lane = tid & 63;
    int rl = lane & 15;
    unsigned swz = (unsigned)((lane & 7) << 4);
    int kq = (lane >> 4) * 16;

    f32x4 acc[2][8];
#pragma unroll
    for (int rt = 0; rt < 2; ++rt)
#pragma unroll
        for (int jt = 0; jt < 8; ++jt)
            acc[rt][jt] = (f32x4){0.f, 0.f, 0.f, 0.f};

    const char* Ab = (const char*)As;
    const char* Bb = (const char*)Bs;
#pragma unroll
    for (int kk = 0; kk < 4; ++kk) {
        int kb = kk * 64 + kq;
        short8 a[2], bfr[8];
        a[0] = *(const short8*)(Ab + (((unsigned)((wv * 32 + rl) * 256 + kb)) ^ swz));
        a[1] = *(const short8*)(Ab + (((unsigned)((wv * 32 + 16 + rl) * 256 + kb)) ^ swz));
#pragma unroll
        for (int jt = 0; jt < 8; ++jt)
            bfr[jt] = *(const short8*)(Bb + (((unsigned)((jt * 16 + rl) * 256 + kb)) ^ swz));
#pragma unroll
        for (int rt = 0; rt < 2; ++rt)
#pragma unroll
            for (int jt = 0; jt < 8; ++jt)
                acc[rt][jt] = __builtin_amdgcn_mfma_f32_16x16x32_bf16(a[rt], bfr[jt], acc[rt][jt], 0, 0, 0);
    }

#pragma unroll
    for (int rt = 0; rt < 2; ++rt) {
        int gr0 = row0 + wv * 32 + rt * 16 + ((lane >> 4) << 2);
#pragma unroll
        for (int jt = 0; jt < 8; ++jt) {
            int col = jt * 16 + rl;
#pragma unroll
            for (int rg = 0; rg < 4; ++rg) {
                int gr = gr0 + rg;
                if (gr < N) ftb[(size_t)gr * 128 + col] = f2bf(acc[rt][jt][rg]);
            }
        }
    }
}

// K7: aggregate: wave per node, bf16 ft rows (256 B), CSR walk unrolled x4
__global__ __launch_bounds__(256) void k_agg(const unsigned* __restrict__ csr,
                                             const unsigned* __restrict__ offs,
                                             const unsigned* __restrict__ deg,
                                             const float* __restrict__ stats,
                                             const float* __restrict__ emb,
                                             const unsigned* __restrict__ ftu,  // bf16 pairs
                                             float* __restrict__ rst, int N) {
    __shared__ float wl[4 * 32];
    int tid = threadIdx.x;
    int wv = tid >> 6, lane = tid & 63;
    int n = blockIdx.x * 4 + wv;
    n = __builtin_amdgcn_readfirstlane(n);
    if (n < N && lane < 32) {
        int tt = lane >> 2, hh = lane & 3;
        float m = stats[(size_t)n * 8 + hh];
        float is = stats[(size_t)n * 8 + 4 + hh];
        wl[wv * 32 + lane] = expf(emb[tt * 4 + hh] - m) * is;
    }
    __syncthreads();
    if (n >= N) return;
    unsigned o = offs[n], dg = deg[n];
    int h = lane >> 4;
    const float* wlh = wl + wv * 32 + h;
    float accx = 0.f, accy = 0.f;
    unsigned k = o, end = o + dg;
    for (; k + 4 <= end; k += 4) {
        unsigned c0 = csr[k], c1 = csr[k + 1], c2 = csr[k + 2], c3 = csr[k + 3];
        unsigned f0 = ftu[(size_t)(c0 & 0xFFFFFu) * 64 + lane];
        unsigned f1 = ftu[(size_t)(c1 & 0xFFFFFu) * 64 + lane];
        unsigned f2 = ftu[(size_t)(c2 & 0xFFFFFu) * 64 + lane];
        unsigned f3 = ftu[(size_t)(c3 & 0xFFFFFu) * 64 + lane];
        float a0 = wlh[(c0 >> 20) * 4];
        float a1 = wlh[(c1 >> 20) * 4];
        float a2 = wlh[(c2 >> 20) * 4];
        float a3 = wlh[(c3 >> 20) * 4];
        accx = fmaf(a0, __builtin_bit_cast(float, f0 << 16), accx);
        accy = fmaf(a0, __builtin_bit_cast(float, f0 & 0xFFFF0000u), accy);
        accx = fmaf(a1, __builtin_bit_cast(float, f1 << 16), accx);
        accy = fmaf(a1, __builtin_bit_cast(float, f1 & 0xFFFF0000u), accy);
        accx = fmaf(a2, __builtin_bit_cast(float, f2 << 16), accx);
        accy = fmaf(a2, __builtin_bit_cast(float, f2 & 0xFFFF0000u), accy);
        accx = fmaf(a3, __builtin_bit_cast(float, f3 << 16), accx);
        accy = fmaf(a3, __builtin_bit_cast(float, f3 & 0xFFFF0000u), accy);
    }
    for (; k < end; ++k) {
        unsigned c0 = csr[k];
        unsigned f0 = ftu[(size_t)(c0 & 0xFFFFFu) * 64 + lane];
        float a0 = wlh[(c0 >> 20) * 4];
        accx = fmaf(a0, __builtin_bit_cast(float, f0 << 16), accx);
        accy = fmaf(a0, __builtin_bit_cast(float, f0 & 0xFFFF0000u), accy);
    }
    ((float2*)rst)[(size_t)n * 64 + lane] = make_float2(accx, accy);
}

extern "C" void kernel_launch(void* const* d_in, const int* in_sizes, int n_in,
                              void* d_out, int out_size, void* d_ws, size_t ws_size,
                              hipStream_t stream) {
    const float* feat = (const float*)d_in[0];
    const float* W = (const float*)d_in[1];
    const float* emb = (const float*)d_in[2];
    const int* e_feat = (const int*)d_in[3];
    const int* src = (const int*)d_in[4];
    const int* dst = (const int*)d_in[5];
    int N = in_sizes[0] / 128;
    int E = in_sizes[3];
    int NBUK = (N + 63) / 64;

    char* ws = (char*)d_ws;
    size_t off = 0;
    auto alloc = [&](size_t bytes) {
        void* p = ws + off;
        off = (off + bytes + 255) & ~(size_t)255;
        return p;
    };
    unsigned short* ftb = (unsigned short*)alloc((size_t)N * 128 * 2);
    unsigned* cnt = (unsigned*)alloc((size_t)N * 8 * 4);
    float* stats = (float*)alloc((size_t)N * 8 * 4);
    unsigned* deg = (unsigned*)alloc((size_t)N * 4);
    unsigned* offs = (unsigned*)alloc((size_t)N * 4);
    unsigned* csr = (unsigned*)alloc((size_t)E * 4);
    unsigned* csr2 = (unsigned*)alloc((size_t)E * 4);
    unsigned* bcur = (unsigned*)alloc((size_t)NBUK * 4);
    unsigned* part = (unsigned*)alloc(4096);
    unsigned* base = (unsigned*)alloc(4096);

    float* rst = (float*)d_out;
    float4* ao = (float4*)((float*)d_out + (size_t)N * 128);

    hipMemsetAsync(cnt, 0, (size_t)N * 8 * 4, stream);
    hipMemsetAsync(bcur, 0, (size_t)NBUK * 4, stream);

    int NB = (N + 255) / 256;
    k_hist<<<(E + 255) / 256, 256, 0, stream>>>(e_feat, dst, cnt, E);
    k_stats<<<NB, 256, 0, stream>>>(cnt, emb, stats, deg, N);
    k_scan_part<<<NB, 256, 0, stream>>>(deg, part, N);
    k_scan_block<<<1, 512, 0, stream>>>(part, base, NB);
    k_scan_offs<<<NB, 256, 0, stream>>>(deg, base, offs, N);
    k_bucket<<<(E + 255) / 256, 256, 0, stream>>>(src, dst, e_feat, offs, bcur, csr2, emb, stats, ao, E);
    k_bsort<<<NBUK, 256, 0, stream>>>(csr2, offs, csr, N, E);
    k_gemm_mfma<<<(N + 127) / 128, 256, 0, stream>>>(feat, W, ftb, N);
    k_agg<<<(N + 3) / 4, 256, 0, stream>>>(csr, offs, deg, stats, emb, (const unsigned*)ftb, rst, N);
}

// Round 5
// 197.400 us; speedup vs baseline: 2.1972x; 2.1972x over previous
//
#include <hip/hip_runtime.h>

// ---------------- constants for this problem ----------------
// N_NODES=100000, N_EDGES=1600000, IN_FEATS=128, H=4, D=32, HD=128, NUM_ETYPES=8, DROP_BLOCKS=4
// Bucket = 512 consecutive dst nodes (nbuk = ceil(N/512) = 196).
// csr2 entry: src[0:17) | etype[17:20) | (dst&511)[20:29)
// csr  entry: src[0:20) | etype[20:23)

typedef short short8 __attribute__((ext_vector_type(8)));
typedef float f32x4 __attribute__((ext_vector_type(4)));

__device__ inline unsigned short f2bf(float x) {
    unsigned u = __builtin_bit_cast(unsigned, x);
    u += 0x7FFFu + ((u >> 16) & 1u);   // RNE
    return (unsigned short)(u >> 16);
}

// K1: coarse bucket histogram (196 buckets of 512 nodes)
__global__ __launch_bounds__(256) void k_bcnt(const int* __restrict__ dst,
                                              unsigned* __restrict__ gcnt, int E) {
    __shared__ unsigned l[256];
    int tid = threadIdx.x;
    l[tid] = 0;
    __syncthreads();
    int base = blockIdx.x * 2048;
#pragma unroll
    for (int j = 0; j < 8; ++j) {
        int e = base + j * 256 + tid;
        if (e < E) atomicAdd(&l[(unsigned)dst[e] >> 9], 1u);
    }
    __syncthreads();
    if (l[tid]) atomicAdd(&gcnt[tid], l[tid]);
}

// K2: exclusive scan of bucket counts (single block, 256 >= nbuk)
__global__ __launch_bounds__(256) void k_bscan(const unsigned* __restrict__ gcnt,
                                               unsigned* __restrict__ gbase,
                                               unsigned* __restrict__ gcur) {
    __shared__ unsigned s[256];
    int t = threadIdx.x;
    unsigned orig = gcnt[t];
    s[t] = orig;
    __syncthreads();
    for (int of = 1; of < 256; of <<= 1) {
        unsigned v = (t >= of) ? s[t - of] : 0u;
        __syncthreads();
        s[t] += v;
        __syncthreads();
    }
    unsigned eb = s[t] - orig;
    gbase[t] = eb;
    gcur[t] = eb;
}

// K3: LDS-staged partition: group 4096-edge chunks by bucket in LDS, reserve
// per-bucket global space (1 atomic per block-bucket), flush coalesced.
__global__ __launch_bounds__(256) void k_part(const int* __restrict__ src,
                                              const int* __restrict__ dst,
                                              const int* __restrict__ ef,
                                              unsigned* __restrict__ gcur,
                                              unsigned* __restrict__ csr2,
                                              int E, int nbuk) {
    __shared__ unsigned lcnt[256];
    __shared__ unsigned lbase[256];
    __shared__ unsigned lcur[256];
    __shared__ unsigned gw2[256];
    __shared__ unsigned stp[4096];
    __shared__ unsigned short stb[4096];
    int tid = threadIdx.x;
    lcnt[tid] = 0;
    __syncthreads();

    int cb = blockIdx.x * 4096;
    int cc = E - cb; if (cc > 4096) cc = 4096;

    unsigned pay[16];
    unsigned short bk[16];
#pragma unroll
    for (int j = 0; j < 16; ++j) {
        int idx = j * 256 + tid;
        if (idx < cc) {
            int e = cb + idx;
            unsigned d = (unsigned)dst[e];
            pay[j] = (unsigned)src[e] | ((unsigned)ef[e] << 17) | ((d & 511u) << 20);
            bk[j] = (unsigned short)(d >> 9);
            atomicAdd(&lcnt[bk[j]], 1u);
        }
    }
    __syncthreads();
    // scan lcnt -> exclusive lbase
    lbase[tid] = lcnt[tid];
    __syncthreads();
    for (int of = 1; of < 256; of <<= 1) {
        unsigned v = (tid >= of) ? lbase[tid - of] : 0u;
        __syncthreads();
        lbase[tid] += v;
        __syncthreads();
    }
    unsigned eb = lbase[tid] - lcnt[tid];
    __syncthreads();
    lbase[tid] = eb;
    lcur[tid] = eb;
    __syncthreads();
    // LDS scatter: group by bucket
#pragma unroll
    for (int j = 0; j < 16; ++j) {
        int idx = j * 256 + tid;
        if (idx < cc) {
            unsigned lpos = atomicAdd(&lcur[bk[j]], 1u);
            stp[lpos] = pay[j];
            stb[lpos] = bk[j];
        }
    }
    // reserve global space
    if (tid < nbuk && lcnt[tid]) gw2[tid] = atomicAdd(&gcur[tid], lcnt[tid]);
    __syncthreads();
    // coalesced flush
#pragma unroll
    for (int j = 0; j < 16; ++j) {
        int i = j * 256 + tid;
        if (i < cc) {
            unsigned b = stb[i];
            csr2[gw2[b] + (i - lbase[b])] = stp[i];
        }
    }
}

// K4: per-bucket: count (node,etype), scan node degrees -> offs/deg/stats,
// then counting-sort into final node-grouped CSR (L2-hot region).
__global__ __launch_bounds__(256) void k_bsort2(const unsigned* __restrict__ csr2,
                                                const unsigned* __restrict__ gbase,
                                                const unsigned* __restrict__ gcnt,
                                                const float* __restrict__ emb,
                                                unsigned* __restrict__ csr,
                                                unsigned* __restrict__ offs,
                                                unsigned* __restrict__ deg,
                                                float* __restrict__ stats, int N) {
    __shared__ unsigned cnt8[512 * 8];   // 16 KB
    __shared__ unsigned degL[512];
    __shared__ unsigned offsL[512];
    __shared__ unsigned curL[512];
    __shared__ unsigned tmp[256];
    __shared__ float se[32];
    int b = blockIdx.x, tid = threadIdx.x;
    if (tid < 32) se[tid] = emb[tid];
#pragma unroll
    for (int i = 0; i < 16; ++i) cnt8[i * 256 + tid] = 0u;
    __syncthreads();
    unsigned r0 = gbase[b], r1 = r0 + gcnt[b];
    for (unsigned i = r0 + tid; i < r1; i += 256) {
        unsigned en = csr2[i];
        atomicAdd(&cnt8[((en >> 20) & 511u) * 8u + ((en >> 17) & 7u)], 1u);
    }
    __syncthreads();
    int n0 = tid * 2, n1 = tid * 2 + 1;
    unsigned d0 = 0, d1 = 0;
#pragma unroll
    for (int k = 0; k < 8; ++k) { d0 += cnt8[n0 * 8 + k]; d1 += cnt8[n1 * 8 + k]; }
    degL[n0] = d0; degL[n1] = d1;
    tmp[tid] = d0 + d1;
    __syncthreads();
    for (int of = 1; of < 256; of <<= 1) {
        unsigned v = (tid >= of) ? tmp[tid - of] : 0u;
        __syncthreads();
        tmp[tid] += v;
        __syncthreads();
    }
    unsigned eb = tmp[tid] - (d0 + d1);
    offsL[n0] = eb;        curL[n0] = eb;
    offsL[n1] = eb + d0;   curL[n1] = eb + d0;
    // per-node outputs + fused softmax stats
#pragma unroll
    for (int q = 0; q < 2; ++q) {
        int nl = tid * 2 + q;
        int gn = b * 512 + nl;
        if (gn < N) {
            offs[gn] = r0 + offsL[nl];
            unsigned dg = degL[nl];
            deg[gn] = dg;
            const unsigned* c = &cnt8[nl * 8];
#pragma unroll
            for (int h = 0; h < 4; ++h) {
                float m = -3.4e38f;
#pragma unroll
                for (int tt = 0; tt < 8; ++tt)
                    if (c[tt]) m = fmaxf(m, se[tt * 4 + h]);
                float s = 0.f;
#pragma unroll
                for (int tt = 0; tt < 8; ++tt)
                    if (c[tt]) s += (float)c[tt] * expf(se[tt * 4 + h] - m);
                stats[(size_t)gn * 8 + h] = m;
                stats[(size_t)gn * 8 + 4 + h] = dg ? (1.0f / s) : 0.0f;
            }
        }
    }
    __syncthreads();
    // counting-sort scatter within the (L2-hot) bucket region
    for (unsigned i = r0 + tid; i < r1; i += 256) {
        unsigned en = csr2[i];
        unsigned nlo = (en >> 20) & 511u;
        unsigned tt = (en >> 17) & 7u;
        unsigned pos = r0 + atomicAdd(&curL[nlo], 1u);
        csr[pos] = (en & 0x1FFFFu) | (tt << 20);
    }
}

// K5: attn_out (E, H, 4, 1)
__global__ void k_attn_out(const int* __restrict__ e_feat, const int* __restrict__ dst,
                           const float* __restrict__ emb, const float* __restrict__ stats,
                           float4* __restrict__ ao, int E4) {
    int i = blockIdx.x * 256 + threadIdx.x;
    if (i >= E4) return;
    int e = i >> 2, h = i & 3;
    int tt = e_feat[e];
    int d = dst[e];
    float a = expf(emb[tt * 4 + h] - stats[(size_t)d * 8 + h]) * stats[(size_t)d * 8 + 4 + h];
    ao[i] = make_float4(a, a, a, a);
}

// K6: ft = feat @ W^T via bf16 MFMA; output stored as bf16 for the gather.
__global__ __launch_bounds__(256) void k_gemm_mfma(const float* __restrict__ feat,
                                                   const float* __restrict__ W,
                                                   unsigned short* __restrict__ ftb, int N) {
    __shared__ unsigned short As[128 * 128];  // 32 KB
    __shared__ unsigned short Bs[128 * 128];  // 32 KB
    int tid = threadIdx.x;
    int row0 = blockIdx.x * 128;

#pragma unroll
    for (int it = 0; it < 16; ++it) {
        int i = it * 1024 + tid * 4;
        int r = i >> 7, c = i & 127;
        unsigned swz = (unsigned)((r & 7) << 4);
        float4 w4 = *(const float4*)(W + i);
        ushort4 wb;
        wb.x = f2bf(w4.x); wb.y = f2bf(w4.y); wb.z = f2bf(w4.z); wb.w = f2bf(w4.w);
        *(ushort4*)((char*)Bs + (((unsigned)(r * 256 + c * 2)) ^ swz)) = wb;
        int gr = row0 + r;
        float4 a4 = make_float4(0.f, 0.f, 0.f, 0.f);
        if (gr < N) a4 = *(const float4*)(feat + (size_t)gr * 128 + c);
        ushort4 ab;
        ab.x = f2bf(a4.x); ab.y = f2bf(a4.y); ab.z = f2bf(a4.z); ab.w = f2bf(a4.w);
        *(ushort4*)((char*)As + (((unsigned)(r * 256 + c * 2)) ^ swz)) = ab;
    }
    __syncthreads();

    int wv = tid >> 6, lane = tid & 63;
    int rl = lane & 15;
    unsigned swz = (unsigned)((lane & 7) << 4);
    int kq = (lane >> 4) * 16;

    f32x4 acc[2][8];
#pragma unroll
    for (int rt = 0; rt < 2; ++rt)
#pragma unroll
        for (int jt = 0; jt < 8; ++jt)
            acc[rt][jt] = (f32x4){0.f, 0.f, 0.f, 0.f};

    const char* Ab = (const char*)As;
    const char* Bb = (const char*)Bs;
#pragma unroll
    for (int kk = 0; kk < 4; ++kk) {
        int kb = kk * 64 + kq;
        short8 a[2], bfr[8];
        a[0] = *(const short8*)(Ab + (((unsigned)((wv * 32 + rl) * 256 + kb)) ^ swz));
        a[1] = *(const short8*)(Ab + (((unsigned)((wv * 32 + 16 + rl) * 256 + kb)) ^ swz));
#pragma unroll
        for (int jt = 0; jt < 8; ++jt)
            bfr[jt] = *(const short8*)(Bb + (((unsigned)((jt * 16 + rl) * 256 + kb)) ^ swz));
#pragma unroll
        for (int rt = 0; rt < 2; ++rt)
#pragma unroll
            for (int jt = 0; jt < 8; ++jt)
                acc[rt][jt] = __builtin_amdgcn_mfma_f32_16x16x32_bf16(a[rt], bfr[jt], acc[rt][jt], 0, 0, 0);
    }

#pragma unroll
    for (int rt = 0; rt < 2; ++rt) {
        int gr0 = row0 + wv * 32 + rt * 16 + ((lane >> 4) << 2);
#pragma unroll
        for (int jt = 0; jt < 8; ++jt) {
            int col = jt * 16 + rl;
#pragma unroll
            for (int rg = 0; rg < 4; ++rg) {
                int gr = gr0 + rg;
                if (gr < N) ftb[(size_t)gr * 128 + col] = f2bf(acc[rt][jt][rg]);
            }
        }
    }
}

// K7: aggregate: wave per node, bf16 ft rows (256 B), CSR walk unrolled x4
__global__ __launch_bounds__(256) void k_agg(const unsigned* __restrict__ csr,
                                             const unsigned* __restrict__ offs,
                                             const unsigned* __restrict__ deg,
                                             const float* __restrict__ stats,
                                             const float* __restrict__ emb,
                                             const unsigned* __restrict__ ftu,  // bf16 pairs
                                             float* __restrict__ rst, int N) {
    __shared__ float wl[4 * 32];
    int tid = threadIdx.x;
    int wv = tid >> 6, lane = tid & 63;
    int n = blockIdx.x * 4 + wv;
    n = __builtin_amdgcn_readfirstlane(n);
    if (n < N && lane < 32) {
        int tt = lane >> 2, hh = lane & 3;
        float m = stats[(size_t)n * 8 + hh];
        float is = stats[(size_t)n * 8 + 4 + hh];
        wl[wv * 32 + lane] = expf(emb[tt * 4 + hh] - m) * is;
    }
    __syncthreads();
    if (n >= N) return;
    unsigned o = offs[n], dg = deg[n];
    int h = lane >> 4;
    const float* wlh = wl + wv * 32 + h;
    float accx = 0.f, accy = 0.f;
    unsigned k = o, end = o + dg;
    for (; k + 4 <= end; k += 4) {
        unsigned c0 = csr[k], c1 = csr[k + 1], c2 = csr[k + 2], c3 = csr[k + 3];
        unsigned f0 = ftu[(size_t)(c0 & 0xFFFFFu) * 64 + lane];
        unsigned f1 = ftu[(size_t)(c1 & 0xFFFFFu) * 64 + lane];
        unsigned f2 = ftu[(size_t)(c2 & 0xFFFFFu) * 64 + lane];
        unsigned f3 = ftu[(size_t)(c3 & 0xFFFFFu) * 64 + lane];
        float a0 = wlh[(c0 >> 20) * 4];
        float a1 = wlh[(c1 >> 20) * 4];
        float a2 = wlh[(c2 >> 20) * 4];
        float a3 = wlh[(c3 >> 20) * 4];
        accx = fmaf(a0, __builtin_bit_cast(float, f0 << 16), accx);
        accy = fmaf(a0, __builtin_bit_cast(float, f0 & 0xFFFF0000u), accy);
        accx = fmaf(a1, __builtin_bit_cast(float, f1 << 16), accx);
        accy = fmaf(a1, __builtin_bit_cast(float, f1 & 0xFFFF0000u), accy);
        accx = fmaf(a2, __builtin_bit_cast(float, f2 << 16), accx);
        accy = fmaf(a2, __builtin_bit_cast(float, f2 & 0xFFFF0000u), accy);
        accx = fmaf(a3, __builtin_bit_cast(float, f3 << 16), accx);
        accy = fmaf(a3, __builtin_bit_cast(float, f3 & 0xFFFF0000u), accy);
    }
    for (; k < end; ++k) {
        unsigned c0 = csr[k];
        unsigned f0 = ftu[(size_t)(c0 & 0xFFFFFu) * 64 + lane];
        float a0 = wlh[(c0 >> 20) * 4];
        accx = fmaf(a0, __builtin_bit_cast(float, f0 << 16), accx);
        accy = fmaf(a0, __builtin_bit_cast(float, f0 & 0xFFFF0000u), accy);
    }
    ((float2*)rst)[(size_t)n * 64 + lane] = make_float2(accx, accy);
}

extern "C" void kernel_launch(void* const* d_in, const int* in_sizes, int n_in,
                              void* d_out, int out_size, void* d_ws, size_t ws_size,
                              hipStream_t stream) {
    const float* feat = (const float*)d_in[0];
    const float* W = (const float*)d_in[1];
    const float* emb = (const float*)d_in[2];
    const int* e_feat = (const int*)d_in[3];
    const int* src = (const int*)d_in[4];
    const int* dst = (const int*)d_in[5];
    int N = in_sizes[0] / 128;
    int E = in_sizes[3];
    int nbuk = (N + 511) >> 9;

    char* ws = (char*)d_ws;
    size_t off = 0;
    auto alloc = [&](size_t bytes) {
        void* p = ws + off;
        off = (off + bytes + 255) & ~(size_t)255;
        return p;
    };
    unsigned short* ftb = (unsigned short*)alloc((size_t)N * 128 * 2);
    float* stats = (float*)alloc((size_t)N * 8 * 4);
    unsigned* deg = (unsigned*)alloc((size_t)N * 4);
    unsigned* offs = (unsigned*)alloc((size_t)N * 4);
    unsigned* csr = (unsigned*)alloc((size_t)E * 4);
    unsigned* csr2 = (unsigned*)alloc((size_t)E * 4);
    unsigned* gcnt = (unsigned*)alloc(256 * 4);
    unsigned* gbase = (unsigned*)alloc(256 * 4);
    unsigned* gcur = (unsigned*)alloc(256 * 4);

    float* rst = (float*)d_out;
    float4* ao = (float4*)((float*)d_out + (size_t)N * 128);

    hipMemsetAsync(gcnt, 0, 256 * 4, stream);

    k_bcnt<<<(E + 2047) / 2048, 256, 0, stream>>>(dst, gcnt, E);
    k_bscan<<<1, 256, 0, stream>>>(gcnt, gbase, gcur);
    k_part<<<(E + 4095) / 4096, 256, 0, stream>>>(src, dst, e_feat, gcur, csr2, E, nbuk);
    k_bsort2<<<nbuk, 256, 0, stream>>>(csr2, gbase, gcnt, emb, csr, offs, deg, stats, N);
    k_attn_out<<<(E * 4 + 255) / 256, 256, 0, stream>>>(e_feat, dst, emb, stats, ao, E * 4);
    k_gemm_mfma<<<(N + 127) / 128, 256, 0, stream>>>(feat, W, ftb, N);
    k_agg<<<(N + 3) / 4, 256, 0, stream>>>(csr, offs, deg, stats, emb, (const unsigned*)ftb, rst, N);
}